// Round 11
// baseline (407.016 us; speedup 1.0000x reference)
//
#include <hip/hip_runtime.h>
#include <hip/hip_bf16.h>
#include <math.h>

// ---------------------------------------------------------------------------
// GATv2 x2 + Linear. CSR via dst-binned counting sort (no global atomics) +
// bf16 MFMA GEMM (dual-fused) + softmax aggregates.
// Round 20: agg1 is L2-miss-BW bound (FETCH pinned 88MB, dur 46us across 6
// scheduling/issue variants). GAT heads are independent -> layer-1 tensors
// go HEAD-MAJOR [8][N][16] and gat_agg_h runs 8 temporal head-phases
// (blockIdx head-major; HW dispatch order sweeps heads). Each phase gathers
// from a 1.6MB slice that fits every XCD's 4MB L2 -> gather becomes L2-hit.
// gemm_dual L1 epilogue writes head-major; gemm_dual L2 loader reads h1
// head-major. agg2 keeps the verified R17 row-major form.
// ---------------------------------------------------------------------------

#define NEG_SLOPE 0.2f

typedef __attribute__((ext_vector_type(8))) short short8;
typedef __attribute__((ext_vector_type(4))) float f32x4;
typedef __attribute__((ext_vector_type(2))) float f32x2;

__device__ __forceinline__ unsigned short f2bf(float f) {
    unsigned u = __float_as_uint(f);
    u += 0x7FFF + ((u >> 16) & 1);   // RNE
    return (unsigned short)(u >> 16);
}
__device__ __forceinline__ unsigned pack2(float a, float b) {
    return (unsigned)f2bf(a) | ((unsigned)f2bf(b) << 16);
}
__device__ __forceinline__ void unp2(unsigned u, float& lo, float& hi) {
    lo = __uint_as_float(u << 16);
    hi = __uint_as_float(u & 0xffff0000u);
}
__device__ __forceinline__ f32x2 unp2v(unsigned u) {
    f32x2 r;
    r.x = __uint_as_float(u << 16);
    r.y = __uint_as_float(u & 0xffff0000u);
    return r;
}

// compute int32-vs-int64 flag locally: sample ei[1,3,...,511].
__device__ __forceinline__ int local_flag(const int* __restrict__ ei,
                                          int twoE, int* anyf) {
    if (threadIdx.x == 0) *anyf = 0;
    __syncthreads();
    int idx = 2 * (int)threadIdx.x + 1;
    if (idx < twoE && ei[idx] != 0) atomicOr(anyf, 1);
    __syncthreads();
    return *anyf;   // 1 => int32, 0 => int64
}

// --- CSR build pass 1: bin histogram of dst (+ fused weight prep) ----------
__global__ __launch_bounds__(256) void bin_hist(const int* __restrict__ ei,
                                                int* __restrict__ counts,
                                                int E, int Et, int nbins,
                                                const float* __restrict__ Wl1,
                                                const float* __restrict__ Wr1,
                                                const float* __restrict__ Wl2,
                                                const float* __restrict__ Wr2,
                                                const float* __restrict__ Wlin,
                                                unsigned short* __restrict__ Wt) {
    __shared__ int hist[256];
    __shared__ int anyf;
    int blk = blockIdx.x;
    int t = threadIdx.x;
    for (int i = t; i < nbins; i += 256) hist[i] = 0;
    int fl = local_flag(ei, 2 * E, &anyf);   // includes the needed syncs
    int e0 = blk * 2048;
    #pragma unroll
    for (int i = 0; i < 8; ++i) {
        int e = e0 + t + i * 256;
        if (e < Et) {
            int d;
            if (e < E) d = fl ? ei[E + e] : ei[2 * (E + e)];
            else       d = e - E;  // self loop
            atomicAdd(&hist[d >> 8], 1);
        }
    }
    __syncthreads();
    for (int i = t; i < nbins; i += 256)
        counts[(size_t)blk * nbins + i] = hist[i];

    // fused weight prep: fp32 [K][M] -> bf16 transposed [M][K+8]
    if (blk < 224) {
        int idx = blk * 256 + t;
        if (idx < 16384) {
            int k = idx >> 7, c = idx & 127;
            Wt[c * 136 + k] = f2bf(Wl1[idx]);
        } else if (idx < 32768) {
            int j = idx - 16384; int k = j >> 7, c = j & 127;
            Wt[17408 + c * 136 + k] = f2bf(Wr1[j]);
        } else if (idx < 40960) {
            int j = idx - 32768; int k = j >> 6, c = j & 63;
            Wt[34816 + c * 136 + k] = f2bf(Wl2[j]);
        } else if (idx < 49152) {
            int j = idx - 40960; int k = j >> 6, c = j & 63;
            Wt[43520 + c * 136 + k] = f2bf(Wr2[j]);
        } else if (idx < 57344) {
            int j = idx - 49152; int k = j >> 7, c = j & 127;
            Wt[52224 + c * 72 + k] = f2bf(Wlin[j]);
        }
    }
}

// --- generic pass 2: per-bin exclusive scan across blocks ------------------
__global__ __launch_bounds__(256) void scanA(int* __restrict__ counts,
                                             int* __restrict__ bintot,
                                             int nblk, int nbins) {
    __shared__ int sh[256];
    int bin = blockIdx.x;
    int t = threadIdx.x;
    int run = 0;
    for (int base = 0; base < nblk; base += 256) {
        int blk = base + t;
        int v = (blk < nblk) ? counts[(size_t)blk * nbins + bin] : 0;
        sh[t] = v;
        __syncthreads();
        for (int off = 1; off < 256; off <<= 1) {
            int u = (t >= off) ? sh[t - off] : 0;
            __syncthreads();
            sh[t] += u;
            __syncthreads();
        }
        if (blk < nblk) counts[(size_t)blk * nbins + bin] = run + sh[t] - v;
        run += sh[255];
        __syncthreads();
    }
    if (t == 0) bintot[bin] = run;
}

// --- CSR build pass 3: partition edges into bin-contiguous part[] ----------
__global__ __launch_bounds__(256) void bin_part(const int* __restrict__ ei,
                                                const int* __restrict__ bintot,
                                                const int* __restrict__ counts,
                                                uint2* __restrict__ part,
                                                int E, int Et, int nbins) {
    __shared__ int cur[256];
    __shared__ int sc[256];
    __shared__ int anyf;
    int blk = blockIdx.x;
    int t = threadIdx.x;
    int fl = local_flag(ei, 2 * E, &anyf);
    int v = (t < nbins) ? bintot[t] : 0;
    sc[t] = v;
    __syncthreads();
    for (int off = 1; off < 256; off <<= 1) {
        int u = (t >= off) ? sc[t - off] : 0;
        __syncthreads();
        sc[t] += u;
        __syncthreads();
    }
    if (t < nbins)
        cur[t] = (sc[t] - v) + counts[(size_t)blk * nbins + t];
    __syncthreads();
    int e0 = blk * 2048;
    #pragma unroll
    for (int i = 0; i < 8; ++i) {
        int e = e0 + t + i * 256;
        if (e < Et) {
            int s, d;
            if (e < E) {
                if (fl) { s = ei[e];     d = ei[E + e]; }          // int32
                else    { s = ei[2 * e]; d = ei[2 * (E + e)]; }    // int64 low
            } else {
                s = d = e - E;  // self loop
            }
            int pos = atomicAdd(&cur[d >> 8], 1);
            part[pos] = make_uint2((unsigned)s, (unsigned)d);
        }
    }
}

// --- CSR build pass 4: per-bin local CSR (one workgroup per bin) -----------
__global__ __launch_bounds__(256) void bin_csr(const uint2* __restrict__ part,
                                               const int* __restrict__ bintot,
                                               int* __restrict__ rowptr,
                                               int* __restrict__ csr_src,
                                               int N, int Et, int nbins) {
    __shared__ int ldeg[256];
    __shared__ int lsc[256];
    __shared__ int sb[2];
    int bin = blockIdx.x;
    int bin0 = bin << 8;
    int t = threadIdx.x;
    int v = (t < nbins) ? bintot[t] : 0;
    lsc[t] = v;
    __syncthreads();
    for (int off = 1; off < 256; off <<= 1) {
        int u = (t >= off) ? lsc[t - off] : 0;
        __syncthreads();
        lsc[t] += u;
        __syncthreads();
    }
    if (t == bin) { sb[0] = lsc[t] - v; sb[1] = lsc[t]; }
    if (bin == 0 && t == 0) rowptr[N] = Et;
    ldeg[t] = 0;
    __syncthreads();
    int ebase = sb[0], eend = sb[1];
    for (int e = ebase + t; e < eend; e += 256)
        atomicAdd(&ldeg[part[e].y - bin0], 1);
    __syncthreads();
    int dv = ldeg[t];
    lsc[t] = dv;
    __syncthreads();
    for (int off = 1; off < 256; off <<= 1) {
        int u = (t >= off) ? lsc[t - off] : 0;
        __syncthreads();
        lsc[t] += u;
        __syncthreads();
    }
    int excl = lsc[t] - dv;         // exclusive prefix within bin
    int node = bin0 + t;
    if (node < N) rowptr[node] = ebase + excl;
    ldeg[t] = ebase + excl;         // reuse as cursor
    __syncthreads();
    for (int e = ebase + t; e < eend; e += 256) {
        uint2 ed = part[e];
        int pos = atomicAdd(&ldeg[ed.y - bin0], 1);
        csr_src[pos] = (int)ed.x;
    }
}

// --- dual bf16 MFMA GEMM: YL = X@WL+bL, YR = X@WR+bR -----------------------
// INHM: X is head-major [K/16][N][16] bf16. OUTHM: Y written head-major
// [M/16][N][16] bf16 (requires OUTBF).
template <int M, int K, int ACT, int INBF, int OUTBF, int INHM, int OUTHM>
__global__ __launch_bounds__(512) void gemm_dual(const void* __restrict__ Xv,
                                                 const unsigned short* __restrict__ WL,
                                                 const unsigned short* __restrict__ WR,
                                                 const float* __restrict__ biasL,
                                                 const float* __restrict__ biasR,
                                                 void* __restrict__ YLv,
                                                 void* __restrict__ YRv,
                                                 int N) {
    constexpr int KPW  = K + 8;
    constexpr int XP   = 72;
    constexpr int COLT = M / 16;
    constexpr int NCH  = K / 64;

    __shared__ short Wc[2][M * 72];
    __shared__ short Xb[128 * XP];

    int tid = threadIdx.x;
    int wave = tid >> 6, lane = tid & 63;
    int side = wave >> 2, wrow = wave & 3;
    int row0 = blockIdx.x * 128;
    int mrow = lane & 15;
    int kq8 = (lane >> 4) * 8;

    f32x4 acc[2][COLT];
    #pragma unroll
    for (int tm = 0; tm < 2; ++tm)
        #pragma unroll
        for (int tn = 0; tn < COLT; ++tn)
            acc[tm][tn] = (f32x4){0.f, 0.f, 0.f, 0.f};

    for (int ch = 0; ch < NCH; ++ch) {
        __syncthreads();
        if (INBF) {
            const unsigned short* X = (const unsigned short*)Xv;
            for (int idx = tid; idx < 128 * 8; idx += 512) {
                int r = idx >> 3, g = (idx & 7) * 8;
                int gr = row0 + r;
                short8 v = {0, 0, 0, 0, 0, 0, 0, 0};
                if (gr < N) {
                    int k = ch * 64 + g;
                    if (INHM)
                        v = *(const short8*)&X[((size_t)(k >> 4) * N + gr) * 16 +
                                               (k & 15)];
                    else
                        v = *(const short8*)&X[(size_t)gr * K + k];
                }
                *(short8*)&Xb[r * XP + g] = v;
            }
        } else {
            const float* X = (const float*)Xv;
            for (int idx = tid; idx < 128 * 16; idx += 512) {
                int r = idx >> 4, kq = (idx & 15) << 2;
                int gr = row0 + r;
                float4 xv = make_float4(0.f, 0.f, 0.f, 0.f);
                if (gr < N) xv = *(const float4*)&X[(size_t)gr * K + ch * 64 + kq];
                uint2 pk;
                pk.x = pack2(xv.x, xv.y);
                pk.y = pack2(xv.z, xv.w);
                *(uint2*)&Xb[r * XP + kq] = pk;
            }
        }
        for (int i = tid; i < 2 * M * 8; i += 512) {
            int sd = (i >= M * 8);
            int j = sd ? i - M * 8 : i;
            int c = j >> 3, g = j & 7;
            const unsigned short* src = sd ? WR : WL;
            *(short8*)&Wc[sd][c * 72 + g * 8] =
                *(const short8*)&src[c * KPW + ch * 64 + g * 8];
        }
        __syncthreads();

        #pragma unroll
        for (int ks = 0; ks < 2; ++ks) {
            short8 a[2], b[COLT];
            #pragma unroll
            for (int tm = 0; tm < 2; ++tm)
                a[tm] = *(const short8*)&Xb[(wrow * 32 + tm * 16 + mrow) * XP +
                                            ks * 32 + kq8];
            #pragma unroll
            for (int tn = 0; tn < COLT; ++tn)
                b[tn] = *(const short8*)&Wc[side][(tn * 16 + mrow) * 72 +
                                                  ks * 32 + kq8];
            #pragma unroll
            for (int tm = 0; tm < 2; ++tm)
                #pragma unroll
                for (int tn = 0; tn < COLT; ++tn)
                    acc[tm][tn] = __builtin_amdgcn_mfma_f32_16x16x32_bf16(
                        a[tm], b[tn], acc[tm][tn], 0, 0, 0);
        }
    }

    const float* bias = side ? biasR : biasL;
    void* Yv = side ? YRv : YLv;
    int q = lane >> 4;
    #pragma unroll
    for (int tn = 0; tn < COLT; ++tn) {
        int col = tn * 16 + mrow;
        float bc = bias[col];
        #pragma unroll
        for (int tm = 0; tm < 2; ++tm) {
            int base = row0 + wrow * 32 + tm * 16 + q * 4;
            #pragma unroll
            for (int r = 0; r < 4; ++r) {
                int gr = base + r;
                float v = acc[tm][tn][r] + bc;
                if (ACT) v = v > 0.f ? v : expm1f(v);
                if (OUTBF) {
                    float other = __shfl_xor(v, 1, 64);
                    if (!(mrow & 1) && gr < N) {
                        if (OUTHM)   // head tn, channel mrow
                            ((unsigned*)Yv)[((size_t)tn * N + gr) * 8 +
                                            (mrow >> 1)] = pack2(v, other);
                        else
                            ((unsigned*)Yv)[(size_t)gr * (M / 2) + (col >> 1)] =
                                pack2(v, other);
                    }
                } else {
                    if (gr < N) ((float*)Yv)[(size_t)gr * M + col] = v;
                }
            }
        }
    }
}

// --- single bf16 MFMA GEMM (final linear) ----------------------------------
template <int M, int K, int ACT, int INBF, int OUTBF>
__global__ __launch_bounds__(256) void gemm_mfma(const void* __restrict__ Xv,
                                                 const unsigned short* __restrict__ Wtg,
                                                 const float* __restrict__ bias,
                                                 void* __restrict__ Yv,
                                                 int N) {
    constexpr int KPW  = K + 8;
    constexpr int XP   = 72;
    constexpr int COLT = M / 16;
    constexpr int NCH  = K / 64;

    __shared__ short Wt[M * KPW];
    __shared__ short Xb[128 * XP];

    int tid = threadIdx.x;
    int wave = tid >> 6, lane = tid & 63;
    int row0 = blockIdx.x * 128;
    int mrow = lane & 15;
    int kq8 = (lane >> 4) * 8;

    for (int i = tid; i < M * KPW / 8; i += 256)
        ((uint4*)Wt)[i] = ((const uint4*)Wtg)[i];

    f32x4 acc[2][COLT];
    #pragma unroll
    for (int tm = 0; tm < 2; ++tm)
        #pragma unroll
        for (int tn = 0; tn < COLT; ++tn)
            acc[tm][tn] = (f32x4){0.f, 0.f, 0.f, 0.f};

    for (int ch = 0; ch < NCH; ++ch) {
        __syncthreads();
        if (INBF) {
            const unsigned short* X = (const unsigned short*)Xv;
            for (int idx = tid; idx < 128 * 8; idx += 256) {
                int r = idx >> 3, g = (idx & 7) * 8;
                int gr = row0 + r;
                short8 v = {0, 0, 0, 0, 0, 0, 0, 0};
                if (gr < N) v = *(const short8*)&X[(size_t)gr * K + ch * 64 + g];
                *(short8*)&Xb[r * XP + g] = v;
            }
        } else {
            const float* X = (const float*)Xv;
            for (int idx = tid; idx < 128 * 16; idx += 256) {
                int r = idx >> 4, kq = (idx & 15) << 2;
                int gr = row0 + r;
                float4 xv = make_float4(0.f, 0.f, 0.f, 0.f);
                if (gr < N) xv = *(const float4*)&X[(size_t)gr * K + ch * 64 + kq];
                uint2 pk;
                pk.x = pack2(xv.x, xv.y);
                pk.y = pack2(xv.z, xv.w);
                *(uint2*)&Xb[r * XP + kq] = pk;
            }
        }
        __syncthreads();

        #pragma unroll
        for (int ks = 0; ks < 2; ++ks) {
            short8 a[2], b[COLT];
            #pragma unroll
            for (int tm = 0; tm < 2; ++tm)
                a[tm] = *(const short8*)&Xb[(wave * 32 + tm * 16 + mrow) * XP +
                                            ks * 32 + kq8];
            #pragma unroll
            for (int tn = 0; tn < COLT; ++tn)
                b[tn] = *(const short8*)&Wt[(tn * 16 + mrow) * KPW +
                                            ch * 64 + ks * 32 + kq8];
            #pragma unroll
            for (int tm = 0; tm < 2; ++tm)
                #pragma unroll
                for (int tn = 0; tn < COLT; ++tn)
                    acc[tm][tn] = __builtin_amdgcn_mfma_f32_16x16x32_bf16(
                        a[tm], b[tn], acc[tm][tn], 0, 0, 0);
        }
    }

    int q = lane >> 4;
    #pragma unroll
    for (int tn = 0; tn < COLT; ++tn) {
        int col = tn * 16 + mrow;
        float bc = bias[col];
        #pragma unroll
        for (int tm = 0; tm < 2; ++tm) {
            int base = row0 + wave * 32 + tm * 16 + q * 4;
            #pragma unroll
            for (int r = 0; r < 4; ++r) {
                int gr = base + r;
                float v = acc[tm][tn][r] + bc;
                if (ACT) v = v > 0.f ? v : expm1f(v);
                if (OUTBF) {
                    float other = __shfl_xor(v, 1, 64);
                    if (!(mrow & 1) && gr < N)
                        ((unsigned*)Yv)[(size_t)gr * (M / 2) + (col >> 1)] =
                            pack2(v, other);
                } else {
                    if (gr < N) ((float*)Yv)[(size_t)gr * M + col] = v;
                }
            }
        }
    }
}

// --- head-phased GATv2 aggregate for layer 1 (H=8, C=16) -------------------
// xl/xr/out head-major [8][N][16] bf16 = [8][N][2] uint4. blockIdx is
// head-major (h = bid/NB) -> HW dispatch sweeps heads as temporal phases,
// each phase's 1.6MB slice L2-resident. Lane-pair per edge (li = lane&1,
// 8 channels each), 32 edges/trip -> most nodes finish in one trip.
// Per-(node,head) accumulation order fixed (csr order) -> replay-safe.
__global__ __launch_bounds__(256) void gat_agg_h(const uint4* __restrict__ xl,
                                                 const uint4* __restrict__ xr,
                                                 const float* __restrict__ att,
                                                 const int* __restrict__ rowptr,
                                                 const int* __restrict__ csr_src,
                                                 const float* __restrict__ bias,
                                                 uint4* __restrict__ outv,
                                                 int N, int NB) {
    int bid = blockIdx.x;
    int h  = bid / NB;
    int nb = bid - h * NB;
    int wave = threadIdx.x >> 6;
    int lane = threadIdx.x & 63;
    int node = nb * 4 + wave;
    if (node >= N) return;
    int sub = lane >> 1;            // edge slot 0..31
    int li  = lane & 1;             // half-row (8 channels)
    int c0  = li * 8;

    // att + xr slice (8 floats, packed f32x2)
    f32x2 a2[4], xr2[4];
    {
        const float4* ap = (const float4*)(att + h * 16 + c0);
        float4 f0 = ap[0], f1 = ap[1];
        a2[0] = (f32x2){f0.x, f0.y}; a2[1] = (f32x2){f0.z, f0.w};
        a2[2] = (f32x2){f1.x, f1.y}; a2[3] = (f32x2){f1.z, f1.w};
        uint4 u = xr[((size_t)h * N + node) * 2 + li];
        xr2[0] = unp2v(u.x); xr2[1] = unp2v(u.y);
        xr2[2] = unp2v(u.z); xr2[3] = unp2v(u.w);
    }

    int start = rowptr[node];
    int deg   = rowptr[node + 1] - start;
    const int* __restrict__ srcp = csr_src + start;
    int emax = deg - 1;
    if (emax < 0) emax = 0;
    size_t hbase = (size_t)h * N;

    float dsum = 0.f;
    f32x2 acc2[4];
    #pragma unroll
    for (int j = 0; j < 4; ++j) acc2[j] = (f32x2){0.f, 0.f};

    auto srcld = [&](int e) -> int { return srcp[e < emax ? e : emax]; };
    auto rowld = [&](int s) -> uint4 {
        return xl[(hbase + (unsigned)s) * 2 + li];
    };

    int e = sub;
    uint4 u = rowld(srcld(e));
    int s_nxt = srcld(e + 32);

    for (int k0 = 0; k0 < deg; k0 += 32, e += 32) {
        f32x2 xc2[4];
        xc2[0] = unp2v(u.x); xc2[1] = unp2v(u.y);
        xc2[2] = unp2v(u.z); xc2[3] = unp2v(u.w);
        if (k0 + 32 < deg) {                      // wave-uniform (rare)
            u = rowld(s_nxt);
            s_nxt = srcld(e + 64);
        }
        float pt;
        if (e < deg) {
            f32x2 pt2 = (f32x2){0.f, 0.f};
            #pragma unroll
            for (int j = 0; j < 4; ++j) {
                f32x2 t = xc2[j] + xr2[j];
                t = __builtin_elementwise_max(t, t * NEG_SLOPE);
                pt2 += t * a2[j];
            }
            pt = pt2.x + pt2.y;
        } else {
            pt = -INFINITY;                       // tail edge -> p = 0
        }
        float part = pt + __shfl_xor(pt, 1, 64);  // full-head logit
        float p = __expf(part);
        dsum += p;
        f32x2 p2 = (f32x2){p, p};
        #pragma unroll
        for (int j = 0; j < 4; ++j) acc2[j] += p2 * xc2[j];
    }

    // merge the 32 edge-slot partials (offs 2..32; li lanes independent)
    #pragma unroll
    for (int off = 2; off < 64; off <<= 1) {
        dsum += __shfl_xor(dsum, off, 64);
        #pragma unroll
        for (int j = 0; j < 4; ++j) {
            acc2[j].x += __shfl_xor(acc2[j].x, off, 64);
            acc2[j].y += __shfl_xor(acc2[j].y, off, 64);
        }
    }

    if (sub == 0) {                 // lanes 0,1 write the two uint4 halves
        float inv = 1.f / dsum;
        const float4* bp = (const float4*)(bias + h * 16 + c0);
        float4 b0 = bp[0], b1 = bp[1];
        float bb[8] = {b0.x, b0.y, b0.z, b0.w, b1.x, b1.y, b1.z, b1.w};
        unsigned o[4];
        #pragma unroll
        for (int j = 0; j < 4; ++j) {
            float v0 = acc2[j].x * inv + bb[2 * j];
            float v1 = acc2[j].y * inv + bb[2 * j + 1];
            v0 = v0 > 0.f ? v0 : expm1f(v0);
            v1 = v1 > 0.f ? v1 : expm1f(v1);
            o[j] = pack2(v0, v1);
        }
        outv[((size_t)h * N + node) * 2 + li] = make_uint4(o[0], o[1], o[2], o[3]);
    }
}

// --- fused GATv2 aggregate (layer 2, row-major; verified R17 form) ---------
template <int H, int C>
__global__ __launch_bounds__(256) void gat_agg(const void* __restrict__ xl,
                                               const void* __restrict__ xr,
                                               const float* __restrict__ att,
                                               const int* __restrict__ rowptr,
                                               const int* __restrict__ csr_src,
                                               const float* __restrict__ bias,
                                               void* __restrict__ outv,
                                               int N) {
    constexpr int CPL = 8;
    constexpr int HC  = H * C;
    constexpr int LPE = HC / CPL;   // lanes per edge row
    constexpr int B   = 64 / LPE;   // edges per wave-iteration
    constexpr int G   = C / CPL;    // lanes per head group

    int wave = threadIdx.x >> 6;
    int lane = threadIdx.x & 63;
    int node = blockIdx.x * 4 + wave;
    if (node >= N) return;
    int sub = lane / LPE;
    int li  = lane & (LPE - 1);
    int c0  = li * CPL;

    float a[CPL], xrr[CPL];
    {
        float4 f0 = ((const float4*)att)[c0 >> 2];
        float4 f1 = ((const float4*)att)[(c0 >> 2) + 1];
        a[0] = f0.x; a[1] = f0.y; a[2] = f0.z; a[3] = f0.w;
        a[4] = f1.x; a[5] = f1.y; a[6] = f1.z; a[7] = f1.w;
        uint4 u = ((const uint4*)xr)[(size_t)node * LPE + li];
        unp2(u.x, xrr[0], xrr[1]); unp2(u.y, xrr[2], xrr[3]);
        unp2(u.z, xrr[4], xrr[5]); unp2(u.w, xrr[6], xrr[7]);
    }

    int start = rowptr[node];
    int deg   = rowptr[node + 1] - start;
    const int* __restrict__ srcp = csr_src + start;
    int emax = deg - 1;
    if (emax < 0) emax = 0;
    const uint4* __restrict__ xlq = (const uint4*)xl;

    float dsum = 0.f;
    float acc[CPL];
    #pragma unroll
    for (int j = 0; j < CPL; ++j) acc[j] = 0.f;

    auto srcld = [&](int e) -> int { return srcp[e < emax ? e : emax]; };

    int e = sub;
    int s0 = srcld(e);
    uint4 u = xlq[(size_t)s0 * LPE + li];
    int s_nxt = srcld(e + B);

    for (int k0 = 0; k0 < deg; k0 += B, e += B) {
        float xc[CPL];
        unp2(u.x, xc[0], xc[1]); unp2(u.y, xc[2], xc[3]);
        unp2(u.z, xc[4], xc[5]); unp2(u.w, xc[6], xc[7]);
        if (k0 + B < deg) {
            u = xlq[(size_t)s_nxt * LPE + li];
            s_nxt = srcld(e + 2 * B);
        }
        float pt;
        if (e < deg) {
            pt = 0.f;
            #pragma unroll
            for (int j = 0; j < CPL; ++j) {
                float t = xc[j] + xrr[j];
                t = fmaxf(t, NEG_SLOPE * t);
                pt = fmaf(t, a[j], pt);
            }
        } else {
            pt = -INFINITY;
        }
        float part = pt;
        #pragma unroll
        for (int off = 1; off < G; off <<= 1)
            part += __shfl_xor(part, off, 64);
        float p = __expf(part);
        dsum += p;
        #pragma unroll
        for (int j = 0; j < CPL; ++j) acc[j] = fmaf(p, xc[j], acc[j]);
    }

    #pragma unroll
    for (int off = LPE; off < 64; off <<= 1) {
        dsum += __shfl_xor(dsum, off, 64);
        #pragma unroll
        for (int j = 0; j < CPL; ++j) acc[j] += __shfl_xor(acc[j], off, 64);
    }

    if (sub == 0) {
        float inv = 1.f / dsum;
        float4 b0 = ((const float4*)bias)[c0 >> 2];
        float4 b1 = ((const float4*)bias)[(c0 >> 2) + 1];
        float bb[CPL] = {b0.x, b0.y, b0.z, b0.w, b1.x, b1.y, b1.z, b1.w};
        unsigned o[4];
        #pragma unroll
        for (int j = 0; j < 4; ++j) {
            float v0 = acc[2 * j]     * inv + bb[2 * j];
            float v1 = acc[2 * j + 1] * inv + bb[2 * j + 1];
            v0 = v0 > 0.f ? v0 : expm1f(v0);
            v1 = v1 > 0.f ? v1 : expm1f(v1);
            o[j] = pack2(v0, v1);
        }
        ((uint4*)outv)[(size_t)node * LPE + li] =
            make_uint4(o[0], o[1], o[2], o[3]);
    }
}

extern "C" void kernel_launch(void* const* d_in, const int* in_sizes, int n_in,
                              void* d_out, int out_size, void* d_ws, size_t ws_size,
                              hipStream_t stream) {
    const float* x    = (const float*)d_in[0];
    const int*   ei   = (const int*)d_in[1];
    const float* Wl1  = (const float*)d_in[2];
    const float* bl1  = (const float*)d_in[3];
    const float* Wr1  = (const float*)d_in[4];
    const float* br1  = (const float*)d_in[5];
    const float* att1 = (const float*)d_in[6];
    const float* bias1= (const float*)d_in[7];
    const float* Wl2  = (const float*)d_in[8];
    const float* bl2  = (const float*)d_in[9];
    const float* Wr2  = (const float*)d_in[10];
    const float* br2  = (const float*)d_in[11];
    const float* att2 = (const float*)d_in[12];
    const float* bias2= (const float*)d_in[13];
    const float* Wlin = (const float*)d_in[14];
    const float* blin = (const float*)d_in[15];
    float* out = (float*)d_out;

    const int F = 128;
    int N  = in_sizes[0] / F;        // 50000
    int E  = in_sizes[1] / 2;        // 800000
    int Et = E + N;                  // + self loops

    auto cdiv = [](long a, long b) { return (int)((a + b - 1) / b); };
    int nbins = cdiv(N, 256);        // bin = dst >> 8  (N <= 65536 here)
    int nblkA = cdiv(Et, 2048);
    int nblkH = nblkA > 224 ? nblkA : 224;   // bin_hist also does prep_w
    int NB = cdiv(N, 4);

    // workspace layout (Wt first for 16B alignment)
    unsigned short* Wt = (unsigned short*)d_ws;   // 61440 shorts
    unsigned* xl1u = (unsigned*)(Wt + 61440);     // N*64 (head-major [8][N][8])
    unsigned* xr1u = xl1u + (size_t)N * 64;       // N*64 (head-major)
    unsigned* h1u  = xr1u + (size_t)N * 64;       // N*64 (head-major)
    unsigned* xl2u = h1u + (size_t)N * 64;        // N*32 (row-major)
    unsigned* xr2u = xl2u + (size_t)N * 32;       // N*32
    unsigned* h2u  = xr2u + (size_t)N * 32;       // N*32
    int* rowptr  = (int*)(h2u + (size_t)N * 32);  // N+1
    int* csr_src = rowptr + N + 1;                // Et
    int* bintot  = csr_src + Et;                  // 256
    int* counts  = bintot + 256;                  // nblkH * nbins
    uint2* part  = (uint2*)(((uintptr_t)(counts + (size_t)nblkH * nbins) + 15)
                            & ~(uintptr_t)15);    // Et

    // CSR build (counting sort by dst bin, no global atomics) + weight prep
    bin_hist<<<nblkH, 256, 0, stream>>>(ei, counts, E, Et, nbins,
                                        Wl1, Wr1, Wl2, Wr2, Wlin, Wt);
    scanA<<<nbins, 256, 0, stream>>>(counts, bintot, nblkH, nbins);
    bin_part<<<nblkA, 256, 0, stream>>>(ei, bintot, counts, part, E, Et, nbins);
    bin_csr<<<nbins, 256, 0, stream>>>(part, bintot, rowptr, csr_src, N, Et, nbins);

    // ---- layer 1 (H=8, C=16): fp32 x -> HEAD-MAJOR bf16 xl1/xr1 ----
    gemm_dual<128, 128, 0, 0, 1, 0, 1><<<cdiv(N, 128), 512, 0, stream>>>(
        x, Wt, Wt + 17408, bl1, br1, xl1u, xr1u, N);
    gat_agg_h<<<NB * 8, 256, 0, stream>>>(
        (const uint4*)xl1u, (const uint4*)xr1u, att1, rowptr, csr_src,
        bias1, (uint4*)h1u, N, NB);

    // ---- layer 2 (H=1, C=64): head-major h1 -> row-major bf16 xl2/xr2 ----
    gemm_dual<64, 128, 0, 1, 1, 1, 0><<<cdiv(N, 128), 512, 0, stream>>>(
        h1u, Wt + 34816, Wt + 43520, bl2, br2, xl2u, xr2u, N);
    gat_agg<1, 64><<<NB, 256, 0, stream>>>(
        xl2u, xr2u, att2, rowptr, csr_src, bias2, h2u, N);

    // ---- final linear + ELU: bf16 h2 -> fp32 d_out ----
    gemm_mfma<128, 64, 1, 1, 0><<<cdiv(N, 128), 256, 0, stream>>>(
        h2u, Wt + 52224, blin, out, N);
}

// Round 12
// 252.248 us; speedup vs baseline: 1.6136x; 1.6136x over previous
//
#include <hip/hip_runtime.h>
#include <hip/hip_bf16.h>
#include <math.h>

// ---------------------------------------------------------------------------
// GATv2 x2 + Linear. CSR via dst-binned counting sort (no global atomics) +
// bf16 MFMA GEMM (dual-fused) + CPL=8 multi-edge NO-MAX softmax aggregate.
// Round 21: R20's head-phased agg regressed 4.7x (per-(node,head) overhead
// x8, L2 phasing never materialized) -> full revert to the R17 optimum
// (254.0us, verified twice). gat_agg L1 ledger: 7 structural attacks all
// neutral/negative with FETCH pinned at 88MB and dur at 46us -> the kernel
// is at the random-256B-gather L2-miss bandwidth floor for this algorithm.
// ---------------------------------------------------------------------------

#define NEG_SLOPE 0.2f

typedef __attribute__((ext_vector_type(8))) short short8;
typedef __attribute__((ext_vector_type(4))) float f32x4;

__device__ __forceinline__ unsigned short f2bf(float f) {
    unsigned u = __float_as_uint(f);
    u += 0x7FFF + ((u >> 16) & 1);   // RNE
    return (unsigned short)(u >> 16);
}
__device__ __forceinline__ unsigned pack2(float a, float b) {
    return (unsigned)f2bf(a) | ((unsigned)f2bf(b) << 16);
}
__device__ __forceinline__ void unp2(unsigned u, float& lo, float& hi) {
    lo = __uint_as_float(u << 16);
    hi = __uint_as_float(u & 0xffff0000u);
}

// compute int32-vs-int64 flag locally: sample ei[1,3,...,511].
// int64 layout -> odd ints are high words of node ids (< 2^31) == 0.
__device__ __forceinline__ int local_flag(const int* __restrict__ ei,
                                          int twoE, int* anyf) {
    if (threadIdx.x == 0) *anyf = 0;
    __syncthreads();
    int idx = 2 * (int)threadIdx.x + 1;
    if (idx < twoE && ei[idx] != 0) atomicOr(anyf, 1);
    __syncthreads();
    return *anyf;   // 1 => int32, 0 => int64
}

// --- CSR build pass 1: bin histogram of dst (+ fused weight prep) ----------
// bin(d) = d >> 8. counts layout: [blk][nbins].
__global__ __launch_bounds__(256) void bin_hist(const int* __restrict__ ei,
                                                int* __restrict__ counts,
                                                int E, int Et, int nbins,
                                                const float* __restrict__ Wl1,
                                                const float* __restrict__ Wr1,
                                                const float* __restrict__ Wl2,
                                                const float* __restrict__ Wr2,
                                                const float* __restrict__ Wlin,
                                                unsigned short* __restrict__ Wt) {
    __shared__ int hist[256];
    __shared__ int anyf;
    int blk = blockIdx.x;
    int t = threadIdx.x;
    for (int i = t; i < nbins; i += 256) hist[i] = 0;
    int fl = local_flag(ei, 2 * E, &anyf);   // includes the needed syncs
    int e0 = blk * 2048;
    #pragma unroll
    for (int i = 0; i < 8; ++i) {
        int e = e0 + t + i * 256;
        if (e < Et) {
            int d;
            if (e < E) d = fl ? ei[E + e] : ei[2 * (E + e)];
            else       d = e - E;  // self loop
            atomicAdd(&hist[d >> 8], 1);
        }
    }
    __syncthreads();
    for (int i = t; i < nbins; i += 256)
        counts[(size_t)blk * nbins + i] = hist[i];

    // fused weight prep: fp32 [K][M] -> bf16 transposed [M][K+8]
    // offsets (shorts): l1=0, r1=17408, l2=34816, r2=43520, lin=52224
    if (blk < 224) {
        int idx = blk * 256 + t;
        if (idx < 16384) {
            int k = idx >> 7, c = idx & 127;
            Wt[c * 136 + k] = f2bf(Wl1[idx]);
        } else if (idx < 32768) {
            int j = idx - 16384; int k = j >> 7, c = j & 127;
            Wt[17408 + c * 136 + k] = f2bf(Wr1[j]);
        } else if (idx < 40960) {
            int j = idx - 32768; int k = j >> 6, c = j & 63;
            Wt[34816 + c * 136 + k] = f2bf(Wl2[j]);
        } else if (idx < 49152) {
            int j = idx - 40960; int k = j >> 6, c = j & 63;
            Wt[43520 + c * 136 + k] = f2bf(Wr2[j]);
        } else if (idx < 57344) {
            int j = idx - 49152; int k = j >> 7, c = j & 127;
            Wt[52224 + c * 72 + k] = f2bf(Wlin[j]);
        }
    }
}

// --- generic pass 2: per-bin exclusive scan across blocks ------------------
// grid = nbins; counts[blk][bin] -> exclusive prefix; bintot[bin] = total.
__global__ __launch_bounds__(256) void scanA(int* __restrict__ counts,
                                             int* __restrict__ bintot,
                                             int nblk, int nbins) {
    __shared__ int sh[256];
    int bin = blockIdx.x;
    int t = threadIdx.x;
    int run = 0;
    for (int base = 0; base < nblk; base += 256) {
        int blk = base + t;
        int v = (blk < nblk) ? counts[(size_t)blk * nbins + bin] : 0;
        sh[t] = v;
        __syncthreads();
        for (int off = 1; off < 256; off <<= 1) {
            int u = (t >= off) ? sh[t - off] : 0;
            __syncthreads();
            sh[t] += u;
            __syncthreads();
        }
        if (blk < nblk) counts[(size_t)blk * nbins + bin] = run + sh[t] - v;
        run += sh[255];
        __syncthreads();
    }
    if (t == 0) bintot[bin] = run;
}

// --- CSR build pass 3: partition edges into bin-contiguous part[] ----------
__global__ __launch_bounds__(256) void bin_part(const int* __restrict__ ei,
                                                const int* __restrict__ bintot,
                                                const int* __restrict__ counts,
                                                uint2* __restrict__ part,
                                                int E, int Et, int nbins) {
    __shared__ int cur[256];
    __shared__ int sc[256];
    __shared__ int anyf;
    int blk = blockIdx.x;
    int t = threadIdx.x;
    int fl = local_flag(ei, 2 * E, &anyf);
    int v = (t < nbins) ? bintot[t] : 0;
    sc[t] = v;
    __syncthreads();
    for (int off = 1; off < 256; off <<= 1) {
        int u = (t >= off) ? sc[t - off] : 0;
        __syncthreads();
        sc[t] += u;
        __syncthreads();
    }
    if (t < nbins)
        cur[t] = (sc[t] - v) + counts[(size_t)blk * nbins + t];
    __syncthreads();
    int e0 = blk * 2048;
    #pragma unroll
    for (int i = 0; i < 8; ++i) {
        int e = e0 + t + i * 256;
        if (e < Et) {
            int s, d;
            if (e < E) {
                if (fl) { s = ei[e];     d = ei[E + e]; }          // int32
                else    { s = ei[2 * e]; d = ei[2 * (E + e)]; }    // int64 low
            } else {
                s = d = e - E;  // self loop
            }
            int pos = atomicAdd(&cur[d >> 8], 1);
            part[pos] = make_uint2((unsigned)s, (unsigned)d);
        }
    }
}

// --- CSR build pass 4: per-bin local CSR (one workgroup per bin) -----------
__global__ __launch_bounds__(256) void bin_csr(const uint2* __restrict__ part,
                                               const int* __restrict__ bintot,
                                               int* __restrict__ rowptr,
                                               int* __restrict__ csr_src,
                                               int N, int Et, int nbins) {
    __shared__ int ldeg[256];
    __shared__ int lsc[256];
    __shared__ int sb[2];
    int bin = blockIdx.x;
    int bin0 = bin << 8;
    int t = threadIdx.x;
    // exclusive scan of bintot -> this bin's [ebase, eend)
    int v = (t < nbins) ? bintot[t] : 0;
    lsc[t] = v;
    __syncthreads();
    for (int off = 1; off < 256; off <<= 1) {
        int u = (t >= off) ? lsc[t - off] : 0;
        __syncthreads();
        lsc[t] += u;
        __syncthreads();
    }
    if (t == bin) { sb[0] = lsc[t] - v; sb[1] = lsc[t]; }
    if (bin == 0 && t == 0) rowptr[N] = Et;
    ldeg[t] = 0;
    __syncthreads();
    int ebase = sb[0], eend = sb[1];
    for (int e = ebase + t; e < eend; e += 256)
        atomicAdd(&ldeg[part[e].y - bin0], 1);
    __syncthreads();
    int dv = ldeg[t];
    lsc[t] = dv;
    __syncthreads();
    for (int off = 1; off < 256; off <<= 1) {
        int u = (t >= off) ? lsc[t - off] : 0;
        __syncthreads();
        lsc[t] += u;
        __syncthreads();
    }
    int excl = lsc[t] - dv;         // exclusive prefix within bin
    int node = bin0 + t;
    if (node < N) rowptr[node] = ebase + excl;
    ldeg[t] = ebase + excl;         // reuse as cursor
    __syncthreads();
    for (int e = ebase + t; e < eend; e += 256) {
        uint2 ed = part[e];
        int pos = atomicAdd(&ldeg[ed.y - bin0], 1);
        csr_src[pos] = (int)ed.x;
    }
}

// --- dual bf16 MFMA GEMM: YL = X@WL+bL, YR = X@WR+bR -----------------------
template <int M, int K, int ACT, int INBF, int OUTBF>
__global__ __launch_bounds__(512) void gemm_dual(const void* __restrict__ Xv,
                                                 const unsigned short* __restrict__ WL,
                                                 const unsigned short* __restrict__ WR,
                                                 const float* __restrict__ biasL,
                                                 const float* __restrict__ biasR,
                                                 void* __restrict__ YLv,
                                                 void* __restrict__ YRv,
                                                 int N) {
    constexpr int KPW  = K + 8;
    constexpr int XP   = 72;
    constexpr int COLT = M / 16;
    constexpr int NCH  = K / 64;

    __shared__ short Wc[2][M * 72];
    __shared__ short Xb[128 * XP];

    int tid = threadIdx.x;
    int wave = tid >> 6, lane = tid & 63;
    int side = wave >> 2, wrow = wave & 3;
    int row0 = blockIdx.x * 128;
    int mrow = lane & 15;
    int kq8 = (lane >> 4) * 8;

    f32x4 acc[2][COLT];
    #pragma unroll
    for (int tm = 0; tm < 2; ++tm)
        #pragma unroll
        for (int tn = 0; tn < COLT; ++tn)
            acc[tm][tn] = (f32x4){0.f, 0.f, 0.f, 0.f};

    for (int ch = 0; ch < NCH; ++ch) {
        __syncthreads();
        if (INBF) {
            const unsigned short* X = (const unsigned short*)Xv;
            for (int idx = tid; idx < 128 * 8; idx += 512) {
                int r = idx >> 3, g = (idx & 7) * 8;
                int gr = row0 + r;
                short8 v = {0, 0, 0, 0, 0, 0, 0, 0};
                if (gr < N) v = *(const short8*)&X[(size_t)gr * K + ch * 64 + g];
                *(short8*)&Xb[r * XP + g] = v;
            }
        } else {
            const float* X = (const float*)Xv;
            for (int idx = tid; idx < 128 * 16; idx += 512) {
                int r = idx >> 4, kq = (idx & 15) << 2;
                int gr = row0 + r;
                float4 xv = make_float4(0.f, 0.f, 0.f, 0.f);
                if (gr < N) xv = *(const float4*)&X[(size_t)gr * K + ch * 64 + kq];
                uint2 pk;
                pk.x = pack2(xv.x, xv.y);
                pk.y = pack2(xv.z, xv.w);
                *(uint2*)&Xb[r * XP + kq] = pk;
            }
        }
        for (int i = tid; i < 2 * M * 8; i += 512) {
            int sd = (i >= M * 8);
            int j = sd ? i - M * 8 : i;
            int c = j >> 3, g = j & 7;
            const unsigned short* src = sd ? WR : WL;
            *(short8*)&Wc[sd][c * 72 + g * 8] =
                *(const short8*)&src[c * KPW + ch * 64 + g * 8];
        }
        __syncthreads();

        #pragma unroll
        for (int ks = 0; ks < 2; ++ks) {
            short8 a[2], b[COLT];
            #pragma unroll
            for (int tm = 0; tm < 2; ++tm)
                a[tm] = *(const short8*)&Xb[(wrow * 32 + tm * 16 + mrow) * XP +
                                            ks * 32 + kq8];
            #pragma unroll
            for (int tn = 0; tn < COLT; ++tn)
                b[tn] = *(const short8*)&Wc[side][(tn * 16 + mrow) * 72 +
                                                  ks * 32 + kq8];
            #pragma unroll
            for (int tm = 0; tm < 2; ++tm)
                #pragma unroll
                for (int tn = 0; tn < COLT; ++tn)
                    acc[tm][tn] = __builtin_amdgcn_mfma_f32_16x16x32_bf16(
                        a[tm], b[tn], acc[tm][tn], 0, 0, 0);
        }
    }

    const float* bias = side ? biasR : biasL;
    void* Yv = side ? YRv : YLv;
    int q = lane >> 4;
    #pragma unroll
    for (int tn = 0; tn < COLT; ++tn) {
        int col = tn * 16 + mrow;
        float bc = bias[col];
        #pragma unroll
        for (int tm = 0; tm < 2; ++tm) {
            int base = row0 + wrow * 32 + tm * 16 + q * 4;
            #pragma unroll
            for (int r = 0; r < 4; ++r) {
                int gr = base + r;
                float v = acc[tm][tn][r] + bc;
                if (ACT) v = v > 0.f ? v : expm1f(v);
                if (OUTBF) {
                    float other = __shfl_xor(v, 1, 64);
                    if (!(mrow & 1) && gr < N)
                        ((unsigned*)Yv)[(size_t)gr * (M / 2) + (col >> 1)] =
                            pack2(v, other);
                } else {
                    if (gr < N) ((float*)Yv)[(size_t)gr * M + col] = v;
                }
            }
        }
    }
}

// --- single bf16 MFMA GEMM (final linear) ----------------------------------
template <int M, int K, int ACT, int INBF, int OUTBF>
__global__ __launch_bounds__(256) void gemm_mfma(const void* __restrict__ Xv,
                                                 const unsigned short* __restrict__ Wtg,
                                                 const float* __restrict__ bias,
                                                 void* __restrict__ Yv,
                                                 int N) {
    constexpr int KPW  = K + 8;
    constexpr int XP   = 72;
    constexpr int COLT = M / 16;
    constexpr int NCH  = K / 64;

    __shared__ short Wt[M * KPW];
    __shared__ short Xb[128 * XP];

    int tid = threadIdx.x;
    int wave = tid >> 6, lane = tid & 63;
    int row0 = blockIdx.x * 128;
    int mrow = lane & 15;
    int kq8 = (lane >> 4) * 8;

    for (int i = tid; i < M * KPW / 8; i += 256)
        ((uint4*)Wt)[i] = ((const uint4*)Wtg)[i];

    f32x4 acc[2][COLT];
    #pragma unroll
    for (int tm = 0; tm < 2; ++tm)
        #pragma unroll
        for (int tn = 0; tn < COLT; ++tn)
            acc[tm][tn] = (f32x4){0.f, 0.f, 0.f, 0.f};

    for (int ch = 0; ch < NCH; ++ch) {
        __syncthreads();
        if (INBF) {
            const unsigned short* X = (const unsigned short*)Xv;
            for (int idx = tid; idx < 128 * 8; idx += 256) {
                int r = idx >> 3, g = (idx & 7) * 8;
                int gr = row0 + r;
                short8 v = {0, 0, 0, 0, 0, 0, 0, 0};
                if (gr < N) v = *(const short8*)&X[(size_t)gr * K + ch * 64 + g];
                *(short8*)&Xb[r * XP + g] = v;
            }
        } else {
            const float* X = (const float*)Xv;
            for (int idx = tid; idx < 128 * 16; idx += 256) {
                int r = idx >> 4, kq = (idx & 15) << 2;
                int gr = row0 + r;
                float4 xv = make_float4(0.f, 0.f, 0.f, 0.f);
                if (gr < N) xv = *(const float4*)&X[(size_t)gr * K + ch * 64 + kq];
                uint2 pk;
                pk.x = pack2(xv.x, xv.y);
                pk.y = pack2(xv.z, xv.w);
                *(uint2*)&Xb[r * XP + kq] = pk;
            }
        }
        __syncthreads();

        #pragma unroll
        for (int ks = 0; ks < 2; ++ks) {
            short8 a[2], b[COLT];
            #pragma unroll
            for (int tm = 0; tm < 2; ++tm)
                a[tm] = *(const short8*)&Xb[(wave * 32 + tm * 16 + mrow) * XP +
                                            ks * 32 + kq8];
            #pragma unroll
            for (int tn = 0; tn < COLT; ++tn)
                b[tn] = *(const short8*)&Wt[(tn * 16 + mrow) * KPW +
                                            ch * 64 + ks * 32 + kq8];
            #pragma unroll
            for (int tm = 0; tm < 2; ++tm)
                #pragma unroll
                for (int tn = 0; tn < COLT; ++tn)
                    acc[tm][tn] = __builtin_amdgcn_mfma_f32_16x16x32_bf16(
                        a[tm], b[tn], acc[tm][tn], 0, 0, 0);
        }
    }

    int q = lane >> 4;
    #pragma unroll
    for (int tn = 0; tn < COLT; ++tn) {
        int col = tn * 16 + mrow;
        float bc = bias[col];
        #pragma unroll
        for (int tm = 0; tm < 2; ++tm) {
            int base = row0 + wave * 32 + tm * 16 + q * 4;
            #pragma unroll
            for (int r = 0; r < 4; ++r) {
                int gr = base + r;
                float v = acc[tm][tn][r] + bc;
                if (ACT) v = v > 0.f ? v : expm1f(v);
                if (OUTBF) {
                    float other = __shfl_xor(v, 1, 64);
                    if (!(mrow & 1) && gr < N)
                        ((unsigned*)Yv)[(size_t)gr * (M / 2) + (col >> 1)] =
                            pack2(v, other);
                } else {
                    if (gr < N) ((float*)Yv)[(size_t)gr * M + col] = v;
                }
            }
        }
    }
}

// --- fused GATv2 aggregate: CPL=8 multi-edge NO-MAX softmax over CSR -------
// (R12/R14/R17 version, verified under graph-replay re-ordering.)
template <int H, int C>
__global__ __launch_bounds__(256) void gat_agg(const void* __restrict__ xl,
                                               const void* __restrict__ xr,
                                               const float* __restrict__ att,
                                               const int* __restrict__ rowptr,
                                               const int* __restrict__ csr_src,
                                               const float* __restrict__ bias,
                                               void* __restrict__ outv,
                                               int N) {
    constexpr int CPL = 8;
    constexpr int HC  = H * C;
    constexpr int LPE = HC / CPL;   // lanes per edge row (16 / 8)
    constexpr int B   = 64 / LPE;   // edges per wave-iteration (4 / 8)
    constexpr int G   = C / CPL;    // lanes per head group (2 / 8)

    int wave = threadIdx.x >> 6;
    int lane = threadIdx.x & 63;
    int node = blockIdx.x * 4 + wave;
    if (node >= N) return;
    int sub = lane / LPE;           // edge slot within batch
    int li  = lane & (LPE - 1);     // lane within edge row
    int c0  = li * CPL;

    // att + xr row slice into registers (8 floats each)
    float a[CPL], xrr[CPL];
    {
        float4 f0 = ((const float4*)att)[c0 >> 2];
        float4 f1 = ((const float4*)att)[(c0 >> 2) + 1];
        a[0] = f0.x; a[1] = f0.y; a[2] = f0.z; a[3] = f0.w;
        a[4] = f1.x; a[5] = f1.y; a[6] = f1.z; a[7] = f1.w;
        uint4 u = ((const uint4*)xr)[(size_t)node * (HC / 8) + li];
        unp2(u.x, xrr[0], xrr[1]); unp2(u.y, xrr[2], xrr[3]);
        unp2(u.z, xrr[4], xrr[5]); unp2(u.w, xrr[6], xrr[7]);
    }

    int start = rowptr[node];
    int deg   = rowptr[node + 1] - start;
    const int* __restrict__ srcp = csr_src + start;
    int emax = deg - 1;
    if (emax < 0) emax = 0;
    const uint4* __restrict__ xlq = (const uint4*)xl;

    float dsum = 0.f;
    float acc[CPL];
    #pragma unroll
    for (int j = 0; j < CPL; ++j) acc[j] = 0.f;

    auto srcld = [&](int e) -> int { return srcp[e < emax ? e : emax]; };

    // software pipeline: src index 2 iterations ahead, row 1 ahead
    int e = sub;
    int s0 = srcld(e);
    uint4 u = xlq[(size_t)s0 * (HC / 8) + li];
    int s_nxt = srcld(e + B);

    for (int k0 = 0; k0 < deg; k0 += B, e += B) {
        float xc[CPL];
        unp2(u.x, xc[0], xc[1]); unp2(u.y, xc[2], xc[3]);
        unp2(u.z, xc[4], xc[5]); unp2(u.w, xc[6], xc[7]);
        if (k0 + B < deg) {                       // wave-uniform branch
            u = xlq[(size_t)s_nxt * (HC / 8) + li];
            s_nxt = srcld(e + 2 * B);
        }
        float pt;
        if (e < deg) {                            // uniform within a sub-slot
            pt = 0.f;
            #pragma unroll
            for (int j = 0; j < CPL; ++j) {
                float t = xc[j] + xrr[j];
                t = fmaxf(t, NEG_SLOPE * t);
                pt = fmaf(t, a[j], pt);
            }
        } else {
            pt = -INFINITY;                       // tail edge -> p = 0
        }
        float part = pt;
        #pragma unroll
        for (int off = 1; off < G; off <<= 1)
            part += __shfl_xor(part, off, 64);
        float p = __expf(part);                   // per-head logit exp
        dsum += p;
        #pragma unroll
        for (int j = 0; j < CPL; ++j) acc[j] = fmaf(p, xc[j], acc[j]);
    }

    // merge the B sub-slot partials (channel c lives in lanes li + k*LPE)
    #pragma unroll
    for (int off = LPE; off < 64; off <<= 1) {
        dsum += __shfl_xor(dsum, off, 64);
        #pragma unroll
        for (int j = 0; j < CPL; ++j) acc[j] += __shfl_xor(acc[j], off, 64);
    }

    if (sub == 0) {
        float inv = 1.f / dsum;
        float4 b0 = ((const float4*)bias)[c0 >> 2];
        float4 b1 = ((const float4*)bias)[(c0 >> 2) + 1];
        float bb[CPL] = {b0.x, b0.y, b0.z, b0.w, b1.x, b1.y, b1.z, b1.w};
        unsigned o[4];
        #pragma unroll
        for (int j = 0; j < 4; ++j) {
            float v0 = acc[2 * j]     * inv + bb[2 * j];
            float v1 = acc[2 * j + 1] * inv + bb[2 * j + 1];
            v0 = v0 > 0.f ? v0 : expm1f(v0);
            v1 = v1 > 0.f ? v1 : expm1f(v1);
            o[j] = pack2(v0, v1);
        }
        ((uint4*)outv)[(size_t)node * (HC / 8) + li] =
            make_uint4(o[0], o[1], o[2], o[3]);
    }
}

extern "C" void kernel_launch(void* const* d_in, const int* in_sizes, int n_in,
                              void* d_out, int out_size, void* d_ws, size_t ws_size,
                              hipStream_t stream) {
    const float* x    = (const float*)d_in[0];
    const int*   ei   = (const int*)d_in[1];
    const float* Wl1  = (const float*)d_in[2];
    const float* bl1  = (const float*)d_in[3];
    const float* Wr1  = (const float*)d_in[4];
    const float* br1  = (const float*)d_in[5];
    const float* att1 = (const float*)d_in[6];
    const float* bias1= (const float*)d_in[7];
    const float* Wl2  = (const float*)d_in[8];
    const float* bl2  = (const float*)d_in[9];
    const float* Wr2  = (const float*)d_in[10];
    const float* br2  = (const float*)d_in[11];
    const float* att2 = (const float*)d_in[12];
    const float* bias2= (const float*)d_in[13];
    const float* Wlin = (const float*)d_in[14];
    const float* blin = (const float*)d_in[15];
    float* out = (float*)d_out;

    const int F = 128;
    int N  = in_sizes[0] / F;        // 50000
    int E  = in_sizes[1] / 2;        // 800000
    int Et = E + N;                  // + self loops

    auto cdiv = [](long a, long b) { return (int)((a + b - 1) / b); };
    int nbins = cdiv(N, 256);        // bin = dst >> 8  (N <= 65536 here)
    int nblkA = cdiv(Et, 2048);
    int nblkH = nblkA > 224 ? nblkA : 224;   // bin_hist also does prep_w

    // workspace layout (Wt first for 16B alignment)
    unsigned short* Wt = (unsigned short*)d_ws;   // 61440 shorts
    unsigned* xl1u = (unsigned*)(Wt + 61440);     // N*64 (bf16 pairs)
    unsigned* xr1u = xl1u + (size_t)N * 64;       // N*64
    unsigned* h1u  = xr1u + (size_t)N * 64;       // N*64
    unsigned* xl2u = h1u + (size_t)N * 64;        // N*32 (bf16 pairs)
    unsigned* xr2u = xl2u + (size_t)N * 32;       // N*32
    unsigned* h2u  = xr2u + (size_t)N * 32;       // N*32
    int* rowptr  = (int*)(h2u + (size_t)N * 32);  // N+1
    int* csr_src = rowptr + N + 1;                // Et
    int* bintot  = csr_src + Et;                  // 256
    int* counts  = bintot + 256;                  // nblkH * nbins
    uint2* part  = (uint2*)(((uintptr_t)(counts + (size_t)nblkH * nbins) + 15)
                            & ~(uintptr_t)15);    // Et

    // CSR build (counting sort by dst bin, no global atomics) + weight prep
    bin_hist<<<nblkH, 256, 0, stream>>>(ei, counts, E, Et, nbins,
                                        Wl1, Wr1, Wl2, Wr2, Wlin, Wt);
    scanA<<<nbins, 256, 0, stream>>>(counts, bintot, nblkH, nbins);
    bin_part<<<nblkA, 256, 0, stream>>>(ei, bintot, counts, part, E, Et, nbins);
    bin_csr<<<nbins, 256, 0, stream>>>(part, bintot, rowptr, csr_src, N, Et, nbins);

    // ---- layer 1 (H=8, C=16, concat): fp32 x -> bf16 xl1/xr1 (fused) ----
    gemm_dual<128, 128, 0, 0, 1><<<cdiv(N, 128), 512, 0, stream>>>(
        x, Wt, Wt + 17408, bl1, br1, xl1u, xr1u, N);
    gat_agg<8, 16><<<cdiv(N, 4), 256, 0, stream>>>(
        xl1u, xr1u, att1, rowptr, csr_src, bias1, h1u, N);

    // ---- layer 2 (H=1, C=64): bf16 h1 -> bf16 xl2/xr2 (fused) ----
    gemm_dual<64, 128, 0, 1, 1><<<cdiv(N, 128), 512, 0, stream>>>(
        h1u, Wt + 34816, Wt + 43520, bl2, br2, xl2u, xr2u, N);
    gat_agg<1, 64><<<cdiv(N, 4), 256, 0, stream>>>(
        xl2u, xr2u, att2, rowptr, csr_src, bias2, h2u, N);

    // ---- final linear + ELU: bf16 h2 -> fp32 d_out ----
    gemm_mfma<128, 64, 1, 1, 0><<<cdiv(N, 128), 256, 0, stream>>>(
        h2u, Wt + 52224, blin, out, N);
}